// Round 1
// baseline (2659.686 us; speedup 1.0000x reference)
//
#include <hip/hip_runtime.h>
#include <math.h>

// GCN forward: N=100000 nodes, IN_DIM=128, D=64, L=4 layers, C=40 classes, E=1.6M edges.
// Strategy: build CSR (by dst) once per call, then gather-based aggregation
// (wave-per-node, lane-per-feature), small GEMMs with weights in registers,
// BN stats via per-wave partial sums + atomics.

#define LEAKY_SLOPE 0.2f
#define BN_EPS 1e-5f

// ---------------- CSR build ----------------

__global__ void hist_kernel(const int* __restrict__ src, const int* __restrict__ dst,
                            int* __restrict__ cnt_src, int* __restrict__ cnt_dst, int E) {
  int i = blockIdx.x * blockDim.x + threadIdx.x;
  int stride = gridDim.x * blockDim.x;
  for (; i < E; i += stride) {
    atomicAdd(&cnt_src[src[i]], 1);
    atomicAdd(&cnt_dst[dst[i]], 1);
  }
}

// Per-node norms + CSR row offsets via wave prefix scan + single global cursor.
__global__ void norm_offsets_kernel(const int* __restrict__ cnt_src, const int* __restrict__ cnt_dst,
                                    float* __restrict__ norm_src, float* __restrict__ norm_dst,
                                    int* __restrict__ row_start, int* __restrict__ cursor,
                                    int* __restrict__ g_cursor, int N) {
  int i = blockIdx.x * blockDim.x + threadIdx.x;
  int lane = threadIdx.x & 63;
  int cs = 0, cd = 0;
  if (i < N) { cs = cnt_src[i]; cd = cnt_dst[i]; }
  if (i < N) {
    norm_src[i] = rsqrtf(fmaxf((float)cs, 1.0f));
    norm_dst[i] = rsqrtf(fmaxf((float)cd, 1.0f));
  }
  // wave-inclusive scan of cd
  int x = cd;
  #pragma unroll
  for (int off = 1; off < 64; off <<= 1) {
    int y = __shfl_up(x, off);
    if (lane >= off) x += y;
  }
  int excl = x - cd;
  int total = __shfl(x, 63);
  int base = 0;
  if (lane == 63) base = atomicAdd(g_cursor, total);
  base = __shfl(base, 63);
  if (i < N) {
    int rs = base + excl;
    row_start[i] = rs;
    cursor[i] = rs;
  }
}

__global__ void fill_kernel(const int* __restrict__ src, const int* __restrict__ dst,
                            int* __restrict__ cursor, int* __restrict__ bucket, int E) {
  int i = blockIdx.x * blockDim.x + threadIdx.x;
  int stride = gridDim.x * blockDim.x;
  for (; i < E; i += stride) {
    int d = dst[i];
    int p = atomicAdd(&cursor[d], 1);
    bucket[p] = src[i];
  }
}

// ---------------- input GEMM: h = V @ W_in + b_in  (128 -> 64) ----------------
// wave per node; lane = output col; W_in column cached in 128 VGPRs.
__global__ void input_gemm_kernel(const float* __restrict__ V, const float* __restrict__ W_in,
                                  const float* __restrict__ b_in, float* __restrict__ h, int N) {
  int gw = (int)((blockIdx.x * blockDim.x + threadIdx.x) >> 6);
  int nw = (int)((gridDim.x * blockDim.x) >> 6);
  int lane = threadIdx.x & 63;
  float w[128];
  #pragma unroll
  for (int k = 0; k < 128; k++) w[k] = W_in[k * 64 + lane];
  float bias = b_in[lane];
  for (int n = gw; n < N; n += nw) {
    float v0 = V[n * 128 + lane];
    float v1 = V[n * 128 + 64 + lane];
    float acc = bias;
    #pragma unroll
    for (int k = 0; k < 64; k++) acc += __shfl(v0, k) * w[k];
    #pragma unroll
    for (int k = 0; k < 64; k++) acc += __shfl(v1, k) * w[64 + k];
    h[n * 64 + lane] = acc;
  }
}

// ---------------- aggregation: agg[n] = norm_dst[n] * sum_{e: dst=n} h[src_e]*norm_src[src_e] ----------------
__global__ void agg_kernel(const float* __restrict__ h, const float* __restrict__ norm_src,
                           const float* __restrict__ norm_dst, const int* __restrict__ row_start,
                           const int* __restrict__ cnt_dst, const int* __restrict__ bucket,
                           float* __restrict__ agg, int N) {
  int wid = (int)((blockIdx.x * blockDim.x + threadIdx.x) >> 6);
  int lane = threadIdx.x & 63;
  if (wid >= N) return;
  int start = row_start[wid];
  int len = cnt_dst[wid];
  float acc = 0.f;
  int j = 0;
  for (; j + 2 <= len; j += 2) {
    int s0 = bucket[start + j];
    int s1 = bucket[start + j + 1];
    float ns0 = norm_src[s0];
    float ns1 = norm_src[s1];
    float h0 = h[s0 * 64 + lane];
    float h1 = h[s1 * 64 + lane];
    acc += h0 * ns0;
    acc += h1 * ns1;
  }
  if (j < len) {
    int s = bucket[start + j];
    acc += h[s * 64 + lane] * norm_src[s];
  }
  agg[wid * 64 + lane] = acc * norm_dst[wid];
}

// ---------------- layer GEMM + BN stats: hc = agg @ W + b; stats += (sum, sumsq) ----------------
__global__ void gemm_stats_kernel(const float* __restrict__ agg, const float* __restrict__ W,
                                  const float* __restrict__ b, float* __restrict__ hc,
                                  float* __restrict__ stats, int N) {
  int gw = (int)((blockIdx.x * blockDim.x + threadIdx.x) >> 6);
  int nw = (int)((gridDim.x * blockDim.x) >> 6);
  int lane = threadIdx.x & 63;
  float w[64];
  #pragma unroll
  for (int d = 0; d < 64; d++) w[d] = W[d * 64 + lane];
  float bias = b[lane];
  float ps = 0.f, pss = 0.f;
  for (int n = gw; n < N; n += nw) {
    float a = agg[n * 64 + lane];
    float acc = bias;
    #pragma unroll
    for (int d = 0; d < 64; d++) acc += __shfl(a, d) * w[d];
    hc[n * 64 + lane] = acc;
    ps += acc;
    pss += acc * acc;
  }
  atomicAdd(&stats[lane], ps);
  atomicAdd(&stats[64 + lane], pss);
}

// ---------------- BN finalize: scale/shift per feature ----------------
__global__ void bn_finalize_kernel(const float* __restrict__ stats, const float* __restrict__ gamma,
                                   const float* __restrict__ beta, float* __restrict__ scsh, int N) {
  int lane = threadIdx.x;
  if (lane < 64) {
    float s = stats[lane];
    float ss = stats[64 + lane];
    float invN = 1.0f / (float)N;
    float mean = s * invN;
    float var = fmaxf(ss * invN - mean * mean, 0.0f);
    float scale = gamma[lane] * rsqrtf(var + BN_EPS);
    float shift = beta[lane] - mean * scale;
    scsh[lane] = scale;
    scsh[64 + lane] = shift;
  }
}

// ---------------- apply: h = leaky(hc*scale+shift) + h (in place) ----------------
__global__ void apply_kernel(const float* __restrict__ hc, const float* __restrict__ scsh,
                             float* __restrict__ h, int total4) {
  int i = blockIdx.x * blockDim.x + threadIdx.x;
  int stride = gridDim.x * blockDim.x;
  for (; i < total4; i += stride) {
    float4 v = ((const float4*)hc)[i];
    float4 r = ((const float4*)h)[i];
    int cb = (i * 4) & 63;
    float o0 = v.x * scsh[cb + 0] + scsh[64 + cb + 0];
    float o1 = v.y * scsh[cb + 1] + scsh[64 + cb + 1];
    float o2 = v.z * scsh[cb + 2] + scsh[64 + cb + 2];
    float o3 = v.w * scsh[cb + 3] + scsh[64 + cb + 3];
    o0 = (o0 >= 0.f) ? o0 : LEAKY_SLOPE * o0;
    o1 = (o1 >= 0.f) ? o1 : LEAKY_SLOPE * o1;
    o2 = (o2 >= 0.f) ? o2 : LEAKY_SLOPE * o2;
    o3 = (o3 >= 0.f) ? o3 : LEAKY_SLOPE * o3;
    float4 o;
    o.x = o0 + r.x; o.y = o1 + r.y; o.z = o2 + r.z; o.w = o3 + r.w;
    ((float4*)h)[i] = o;
  }
}

// ---------------- output: logits = h @ W_out + b_out; log_softmax ----------------
__global__ void out_kernel(const float* __restrict__ h, const float* __restrict__ W_out,
                           const float* __restrict__ b_out, float* __restrict__ out, int N) {
  int gw = (int)((blockIdx.x * blockDim.x + threadIdx.x) >> 6);
  int nw = (int)((gridDim.x * blockDim.x) >> 6);
  int lane = threadIdx.x & 63;
  float w[64];
  #pragma unroll
  for (int d = 0; d < 64; d++) w[d] = (lane < 40) ? W_out[d * 40 + lane] : 0.f;
  float bias = (lane < 40) ? b_out[lane] : 0.f;
  for (int n = gw; n < N; n += nw) {
    float hv = h[n * 64 + lane];
    float acc = bias;
    #pragma unroll
    for (int d = 0; d < 64; d++) acc += __shfl(hv, d) * w[d];
    float lg = (lane < 40) ? acc : -INFINITY;
    float m = lg;
    #pragma unroll
    for (int off = 32; off; off >>= 1) m = fmaxf(m, __shfl_xor(m, off));
    float e = (lane < 40) ? expf(acc - m) : 0.f;
    float s = e;
    #pragma unroll
    for (int off = 32; off; off >>= 1) s += __shfl_xor(s, off);
    float lse = m + logf(s);
    if (lane < 40) out[n * 40 + lane] = acc - lse;
  }
}

extern "C" void kernel_launch(void* const* d_in, const int* in_sizes, int n_in,
                              void* d_out, int out_size, void* d_ws, size_t ws_size,
                              hipStream_t stream) {
  const float* V     = (const float*)d_in[0];
  const int*   src   = (const int*)d_in[1];
  const int*   dst   = (const int*)d_in[2];
  const float* W_in  = (const float*)d_in[3];
  const float* b_in  = (const float*)d_in[4];
  const float* W_l   = (const float*)d_in[5];
  const float* b_l   = (const float*)d_in[6];
  const float* gamma = (const float*)d_in[7];
  const float* beta  = (const float*)d_in[8];
  const float* W_out = (const float*)d_in[9];
  const float* b_out = (const float*)d_in[10];
  float* out = (float*)d_out;

  const int N = in_sizes[0] / 128;  // 100000
  const int E = in_sizes[1];        // 1600000
  const int NL = 4;

  // workspace layout
  char* p = (char*)d_ws;
  auto alloc = [&](size_t bytes) {
    void* r = (void*)p;
    p += (bytes + 255) & ~(size_t)255;
    return r;
  };
  float* h       = (float*)alloc((size_t)N * 64 * 4);
  float* agg     = (float*)alloc((size_t)N * 64 * 4);
  float* hc      = (float*)alloc((size_t)N * 64 * 4);
  int*   bucket  = (int*)alloc((size_t)E * 4);
  int*   cnt_src = (int*)alloc((size_t)N * 4);
  int*   cnt_dst = (int*)alloc((size_t)N * 4);
  int*   row_st  = (int*)alloc((size_t)N * 4);
  int*   cursor  = (int*)alloc((size_t)N * 4);
  float* nrm_src = (float*)alloc((size_t)N * 4);
  float* nrm_dst = (float*)alloc((size_t)N * 4);
  float* stats   = (float*)alloc(128 * 4);
  float* scsh    = (float*)alloc(128 * 4);
  int*   g_cur   = (int*)alloc(256);
  (void)ws_size;

  // zero counters
  hipMemsetAsync(cnt_src, 0, (size_t)N * 4, stream);
  hipMemsetAsync(cnt_dst, 0, (size_t)N * 4, stream);
  hipMemsetAsync(g_cur, 0, 4, stream);

  // CSR build
  hist_kernel<<<2048, 256, 0, stream>>>(src, dst, cnt_src, cnt_dst, E);
  norm_offsets_kernel<<<(N + 255) / 256, 256, 0, stream>>>(cnt_src, cnt_dst, nrm_src, nrm_dst,
                                                           row_st, cursor, g_cur, N);
  fill_kernel<<<2048, 256, 0, stream>>>(src, dst, cursor, bucket, E);

  // input GEMM
  input_gemm_kernel<<<512, 256, 0, stream>>>(V, W_in, b_in, h, N);

  // layers
  for (int l = 0; l < NL; l++) {
    agg_kernel<<<(N * 64 + 255) / 256, 256, 0, stream>>>(h, nrm_src, nrm_dst, row_st, cnt_dst,
                                                         bucket, agg, N);
    hipMemsetAsync(stats, 0, 128 * 4, stream);
    gemm_stats_kernel<<<1024, 256, 0, stream>>>(agg, W_l + (size_t)l * 64 * 64, b_l + (size_t)l * 64,
                                                hc, stats, N);
    bn_finalize_kernel<<<1, 64, 0, stream>>>(stats, gamma + (size_t)l * 64, beta + (size_t)l * 64,
                                             scsh, N);
    apply_kernel<<<2048, 256, 0, stream>>>(hc, scsh, h, N * 64 / 4);
  }

  // output
  out_kernel<<<1024, 256, 0, stream>>>(h, W_out, b_out, out, N);
}

// Round 2
// 1291.624 us; speedup vs baseline: 2.0592x; 2.0592x over previous
//
#include <hip/hip_runtime.h>
#include <math.h>

// GCN forward: N=100000 nodes, IN_DIM=128, D=64, L=4 layers, C=40 classes, E=1.6M edges.
// Round 2: scalar-broadcast GEMMs (wave-per-node, lane=col, weights in VGPRs,
// activation row via readfirstlane->s_load), pre-scaled hs = h*norm_src for the
// gather, bn_finalize fused into apply. __launch_bounds__ everywhere (round-1
// post-mortem: w[128] spilled to scratch at VGPR_Count=64 -> 900MB fetch, 1120us).

#define LEAKY_SLOPE 0.2f
#define BN_EPS 1e-5f

// ---------------- CSR build ----------------

__global__ __launch_bounds__(256, 8)
void hist_kernel(const int* __restrict__ src, const int* __restrict__ dst,
                 int* __restrict__ cnt_src, int* __restrict__ cnt_dst, int E) {
  int i = blockIdx.x * blockDim.x + threadIdx.x;
  int stride = gridDim.x * blockDim.x;
  for (; i < E; i += stride) {
    atomicAdd(&cnt_src[src[i]], 1);
    atomicAdd(&cnt_dst[dst[i]], 1);
  }
}

__global__ __launch_bounds__(256, 8)
void norm_offsets_kernel(const int* __restrict__ cnt_src, const int* __restrict__ cnt_dst,
                         float* __restrict__ norm_src, float* __restrict__ norm_dst,
                         int* __restrict__ row_start, int* __restrict__ cursor,
                         int* __restrict__ g_cursor, int N) {
  int i = blockIdx.x * blockDim.x + threadIdx.x;
  int lane = threadIdx.x & 63;
  int cs = 0, cd = 0;
  if (i < N) { cs = cnt_src[i]; cd = cnt_dst[i]; }
  if (i < N) {
    norm_src[i] = rsqrtf(fmaxf((float)cs, 1.0f));
    norm_dst[i] = rsqrtf(fmaxf((float)cd, 1.0f));
  }
  // wave-inclusive scan of cd
  int x = cd;
  #pragma unroll
  for (int off = 1; off < 64; off <<= 1) {
    int y = __shfl_up(x, off);
    if (lane >= off) x += y;
  }
  int excl = x - cd;
  int total = __shfl(x, 63);
  int base = 0;
  if (lane == 63) base = atomicAdd(g_cursor, total);
  base = __shfl(base, 63);
  if (i < N) {
    int rs = base + excl;
    row_start[i] = rs;
    cursor[i] = rs;
  }
}

__global__ __launch_bounds__(256, 8)
void fill_kernel(const int* __restrict__ src, const int* __restrict__ dst,
                 int* __restrict__ cursor, int* __restrict__ bucket, int E) {
  int i = blockIdx.x * blockDim.x + threadIdx.x;
  int stride = gridDim.x * blockDim.x;
  for (; i < E; i += stride) {
    int d = dst[i];
    int p = atomicAdd(&cursor[d], 1);
    bucket[p] = src[i];
  }
}

// ---------------- input GEMM: h = V @ W_in + b_in (128->64); hs = h*norm_src ----------------
// wave per node; lane = output col; W_in column in 128 VGPRs; V row via scalar loads.
__global__ __launch_bounds__(256, 2)
void input_gemm_kernel(const float* __restrict__ V, const float* __restrict__ W_in,
                       const float* __restrict__ b_in, const float* __restrict__ norm_src,
                       float* __restrict__ h, float* __restrict__ hs, int N) {
  int gw = (int)((blockIdx.x * blockDim.x + threadIdx.x) >> 6);
  int nw = (int)((gridDim.x * blockDim.x) >> 6);
  int lane = threadIdx.x & 63;
  float w[128];
  #pragma unroll
  for (int k = 0; k < 128; k++) w[k] = W_in[k * 64 + lane];
  float bias = b_in[lane];
  for (int n = gw; n < N; n += nw) {
    int ns = __builtin_amdgcn_readfirstlane(n);
    const float* vrow = V + (size_t)ns * 128;   // SGPR base -> s_load
    float acc = bias;
    #pragma unroll
    for (int k = 0; k < 128; k++) acc += vrow[k] * w[k];
    float nsc = norm_src[ns];
    h[(size_t)ns * 64 + lane] = acc;
    hs[(size_t)ns * 64 + lane] = acc * nsc;
  }
}

// ---------------- aggregation: agg[n] = norm_dst[n] * sum_{e: dst=n} hs[src_e] ----------------
__global__ __launch_bounds__(256, 8)
void agg_kernel(const float* __restrict__ hs, const float* __restrict__ norm_dst,
                const int* __restrict__ row_start, const int* __restrict__ cnt_dst,
                const int* __restrict__ bucket, float* __restrict__ agg, int N) {
  int wid = (int)((blockIdx.x * (blockDim.x >> 6)) + (threadIdx.x >> 6));
  wid = __builtin_amdgcn_readfirstlane(wid);
  int lane = threadIdx.x & 63;
  if (wid >= N) return;
  int start = row_start[wid];
  int len = cnt_dst[wid];
  const int* bkt = bucket + start;               // SGPR base -> s_load indices
  float a0 = 0.f, a1 = 0.f, a2 = 0.f, a3 = 0.f;
  int j = 0;
  for (; j + 4 <= len; j += 4) {
    int s0 = bkt[j], s1 = bkt[j + 1], s2 = bkt[j + 2], s3 = bkt[j + 3];
    a0 += hs[(size_t)s0 * 64 + lane];
    a1 += hs[(size_t)s1 * 64 + lane];
    a2 += hs[(size_t)s2 * 64 + lane];
    a3 += hs[(size_t)s3 * 64 + lane];
  }
  for (; j < len; j++) a0 += hs[(size_t)bkt[j] * 64 + lane];
  float acc = (a0 + a1) + (a2 + a3);
  agg[(size_t)wid * 64 + lane] = acc * norm_dst[wid];
}

// ---------------- layer GEMM + BN stats: hc = agg @ W + b; stats += (sum, sumsq) ----------------
__global__ __launch_bounds__(256, 4)
void gemm_stats_kernel(const float* __restrict__ agg, const float* __restrict__ W,
                       const float* __restrict__ b, float* __restrict__ hc,
                       float* __restrict__ stats, int N) {
  int gw = (int)((blockIdx.x * blockDim.x + threadIdx.x) >> 6);
  int nw = (int)((gridDim.x * blockDim.x) >> 6);
  int lane = threadIdx.x & 63;
  float w[64];
  #pragma unroll
  for (int d = 0; d < 64; d++) w[d] = W[d * 64 + lane];
  float bias = b[lane];
  float ps = 0.f, pss = 0.f;
  for (int n = gw; n < N; n += nw) {
    int nsg = __builtin_amdgcn_readfirstlane(n);
    const float* arow = agg + (size_t)nsg * 64;  // SGPR base -> s_load
    float acc = bias;
    #pragma unroll
    for (int d = 0; d < 64; d++) acc += arow[d] * w[d];
    hc[(size_t)nsg * 64 + lane] = acc;
    ps += acc;
    pss += acc * acc;
  }
  atomicAdd(&stats[lane], ps);
  atomicAdd(&stats[64 + lane], pss);
}

// ---------------- fused BN finalize + apply: h = leaky(hc*scale+shift) + h; hs = h*norm_src ----------------
__global__ __launch_bounds__(256, 8)
void apply_kernel(const float* __restrict__ hc, const float* __restrict__ stats,
                  const float* __restrict__ gamma, const float* __restrict__ beta,
                  const float* __restrict__ norm_src, float* __restrict__ h,
                  float* __restrict__ hs, int N) {
  __shared__ float s_scale[64];
  __shared__ float s_shift[64];
  int tid = threadIdx.x;
  if (tid < 64) {
    float s = stats[tid];
    float ss = stats[64 + tid];
    float invN = 1.0f / (float)N;
    float mean = s * invN;
    float var = fmaxf(ss * invN - mean * mean, 0.0f);
    float scale = gamma[tid] * rsqrtf(var + BN_EPS);
    s_scale[tid] = scale;
    s_shift[tid] = beta[tid] - mean * scale;
  }
  __syncthreads();
  int total4 = N * 16;
  int i = blockIdx.x * blockDim.x + threadIdx.x;
  int stride = gridDim.x * blockDim.x;
  for (; i < total4; i += stride) {
    float4 v = ((const float4*)hc)[i];
    float4 r = ((const float4*)h)[i];
    int cb = (i * 4) & 63;
    int n = i >> 4;
    float nsc = norm_src[n];
    float o0 = v.x * s_scale[cb + 0] + s_shift[cb + 0];
    float o1 = v.y * s_scale[cb + 1] + s_shift[cb + 1];
    float o2 = v.z * s_scale[cb + 2] + s_shift[cb + 2];
    float o3 = v.w * s_scale[cb + 3] + s_shift[cb + 3];
    o0 = (o0 >= 0.f) ? o0 : LEAKY_SLOPE * o0;
    o1 = (o1 >= 0.f) ? o1 : LEAKY_SLOPE * o1;
    o2 = (o2 >= 0.f) ? o2 : LEAKY_SLOPE * o2;
    o3 = (o3 >= 0.f) ? o3 : LEAKY_SLOPE * o3;
    float4 oh;
    oh.x = o0 + r.x; oh.y = o1 + r.y; oh.z = o2 + r.z; oh.w = o3 + r.w;
    ((float4*)h)[i] = oh;
    float4 os;
    os.x = oh.x * nsc; os.y = oh.y * nsc; os.z = oh.z * nsc; os.w = oh.w * nsc;
    ((float4*)hs)[i] = os;
  }
}

// ---------------- output: logits = h @ W_out + b_out; log_softmax ----------------
__global__ __launch_bounds__(256, 4)
void out_kernel(const float* __restrict__ h, const float* __restrict__ W_out,
                const float* __restrict__ b_out, float* __restrict__ out, int N) {
  int gw = (int)((blockIdx.x * blockDim.x + threadIdx.x) >> 6);
  int nw = (int)((gridDim.x * blockDim.x) >> 6);
  int lane = threadIdx.x & 63;
  float w[64];
  #pragma unroll
  for (int d = 0; d < 64; d++) w[d] = (lane < 40) ? W_out[d * 40 + lane] : 0.f;
  float bias = (lane < 40) ? b_out[lane] : 0.f;
  for (int n = gw; n < N; n += nw) {
    int nsg = __builtin_amdgcn_readfirstlane(n);
    const float* hrow = h + (size_t)nsg * 64;    // SGPR base -> s_load
    float acc = bias;
    #pragma unroll
    for (int d = 0; d < 64; d++) acc += hrow[d] * w[d];
    float lg = (lane < 40) ? acc : -INFINITY;
    float m = lg;
    #pragma unroll
    for (int off = 32; off; off >>= 1) m = fmaxf(m, __shfl_xor(m, off));
    float e = (lane < 40) ? expf(acc - m) : 0.f;
    float s = e;
    #pragma unroll
    for (int off = 32; off; off >>= 1) s += __shfl_xor(s, off);
    float lse = m + logf(s);
    if (lane < 40) out[(size_t)nsg * 40 + lane] = acc - lse;
  }
}

extern "C" void kernel_launch(void* const* d_in, const int* in_sizes, int n_in,
                              void* d_out, int out_size, void* d_ws, size_t ws_size,
                              hipStream_t stream) {
  const float* V     = (const float*)d_in[0];
  const int*   src   = (const int*)d_in[1];
  const int*   dst   = (const int*)d_in[2];
  const float* W_in  = (const float*)d_in[3];
  const float* b_in  = (const float*)d_in[4];
  const float* W_l   = (const float*)d_in[5];
  const float* b_l   = (const float*)d_in[6];
  const float* gamma = (const float*)d_in[7];
  const float* beta  = (const float*)d_in[8];
  const float* W_out = (const float*)d_in[9];
  const float* b_out = (const float*)d_in[10];
  float* out = (float*)d_out;

  const int N = in_sizes[0] / 128;  // 100000
  const int E = in_sizes[1];        // 1600000
  const int NL = 4;

  // workspace layout
  char* p = (char*)d_ws;
  auto alloc = [&](size_t bytes) {
    void* r = (void*)p;
    p += (bytes + 255) & ~(size_t)255;
    return r;
  };
  float* h       = (float*)alloc((size_t)N * 64 * 4);
  float* agg     = (float*)alloc((size_t)N * 64 * 4);
  float* hc      = (float*)alloc((size_t)N * 64 * 4);  // aliased: also hs (pre-scaled h)
  int*   bucket  = (int*)alloc((size_t)E * 4);
  int*   cnt_src = (int*)alloc((size_t)N * 4);
  int*   cnt_dst = (int*)alloc((size_t)N * 4);
  int*   row_st  = (int*)alloc((size_t)N * 4);
  int*   cursor  = (int*)alloc((size_t)N * 4);
  float* nrm_src = (float*)alloc((size_t)N * 4);
  float* nrm_dst = (float*)alloc((size_t)N * 4);
  float* stats   = (float*)alloc(128 * 4);
  int*   g_cur   = (int*)alloc(256);
  (void)ws_size;
  float* hs = hc;  // alias: hs consumed by agg before gemm_stats rewrites hc

  // zero counters
  hipMemsetAsync(cnt_src, 0, (size_t)N * 4, stream);
  hipMemsetAsync(cnt_dst, 0, (size_t)N * 4, stream);
  hipMemsetAsync(g_cur, 0, 4, stream);

  // CSR build
  hist_kernel<<<2048, 256, 0, stream>>>(src, dst, cnt_src, cnt_dst, E);
  norm_offsets_kernel<<<(N + 255) / 256, 256, 0, stream>>>(cnt_src, cnt_dst, nrm_src, nrm_dst,
                                                           row_st, cursor, g_cur, N);
  fill_kernel<<<2048, 256, 0, stream>>>(src, dst, cursor, bucket, E);

  // input GEMM (also writes hs for layer-0 aggregation)
  input_gemm_kernel<<<512, 256, 0, stream>>>(V, W_in, b_in, nrm_src, h, hs, N);

  // layers
  for (int l = 0; l < NL; l++) {
    agg_kernel<<<(N * 64 + 255) / 256, 256, 0, stream>>>(hs, nrm_dst, row_st, cnt_dst,
                                                         bucket, agg, N);
    hipMemsetAsync(stats, 0, 128 * 4, stream);
    gemm_stats_kernel<<<1024, 256, 0, stream>>>(agg, W_l + (size_t)l * 64 * 64,
                                                b_l + (size_t)l * 64, hc, stats, N);
    apply_kernel<<<2048, 256, 0, stream>>>(hc, stats, gamma + (size_t)l * 64,
                                           beta + (size_t)l * 64, nrm_src, h, hs, N);
  }

  // output
  out_kernel<<<1024, 256, 0, stream>>>(h, W_out, b_out, out, N);
}